// Round 2
// baseline (985.214 us; speedup 1.0000x reference)
//
#include <hip/hip_runtime.h>

// ---- problem constants ----
#define BD    8
#define NPTS  2048
#define FIN   64
#define KNB   32
#define MS    512          // fps samples per graph
#define NH1   128
#define NH2   256
#define NTOT  (BD*NPTS)    // 16384
#define R2F   ((float)(0.1*0.1))

// output layout (floats)
#define XALL_N   (NTOT*NH2)            // 4194304
#define XD_OFF   XALL_N                // x_dst
#define PD_OFF   (XD_OFF + BD*MS*NH2)  // 5242880 pos_dst
#define BT_OFF   (PD_OFF + BD*MS*3)    // 5255168 batch_dst

typedef __attribute__((ext_vector_type(4))) float vf4;

// =====================================================================
// k_radius: 64 blocks x 256 thr; per-point <=32 nearest within r
// =====================================================================
__global__ __launch_bounds__(256) void k_radius(const float* __restrict__ pos,
                                                int* __restrict__ cnt,
                                                int* __restrict__ nbr,
                                                float* __restrict__ nbrd) {
  __shared__ float sP[NPTS * 3];
  const int bid = blockIdx.x, tid = threadIdx.x;
  const int g  = bid >> 3;
  const int ch = bid & 7;
  for (int i = tid; i < NPTS * 3; i += 256) sP[i] = pos[(size_t)g * NPTS * 3 + i];
  __syncthreads();

  const int iL = (ch << 8) + tid;            // graph-local point
  const float mx = sP[iL * 3], my = sP[iL * 3 + 1], mz = sP[iL * 3 + 2];
  const int gi = g * NPTS + iL;
  const long base = (long)gi * KNB;
  int c = 0;
  for (int j = 0; j < NPTS; ++j) {
    float dx = __fsub_rn(sP[j * 3], mx);
    float dy = __fsub_rn(sP[j * 3 + 1], my);
    float dz = __fsub_rn(sP[j * 3 + 2], mz);
    float d2 = __fadd_rn(__fadd_rn(__fmul_rn(dx, dx), __fmul_rn(dy, dy)),
                         __fmul_rn(dz, dz));
    if (d2 <= R2F && j != iL) {
      if (c < KNB) {
        nbr[base + c] = j; nbrd[base + c] = d2; ++c;
      } else {                                   // rare: keep 32 smallest
        int mk = 0; float mv = nbrd[base];
        for (int k2 = 1; k2 < KNB; ++k2) {
          float v = nbrd[base + k2];
          if (v > mv) { mv = v; mk = k2; }
        }
        if (d2 < mv) { nbr[base + mk] = j; nbrd[base + mk] = d2; }
      }
    }
  }
  cnt[gi] = c;
}

// =====================================================================
// k_conv: blocks 0..7 = FPS (overlapped); blocks 8..1031 = edge MLP
// LDS is aliased between the two roles via smem[].
// =====================================================================
#define SMEM_BYTES 46848
// conv-role layout (16B-aligned sections)
#define OFF_FT     0        // float [67][36]  = 9648
#define OFF_H1T    9648     // float [128][36] = 18432
#define OFF_AGG    28080    // uint  [16][256] = 16384
#define OFF_EPTS   44464    // short [512]     = 1024
#define OFF_EJS    45488    // short [512]     = 1024
#define OFF_STARTS 46512    // int   [17]      = 68
#define OFF_SCNT   46580    // int   [16]      = 64
#define OFF_SPPOS  46644    // float [16][3]   = 192  -> ends 46836
// fps-role layout
#define OFF_SP     0        // float [2048*3] = 24576
#define OFF_SV     24576    // float [2][4]
#define OFF_SI     24608    // int   [2][4]

__global__ __launch_bounds__(256) void k_conv(const float* __restrict__ x,
                                              const float* __restrict__ pos,
                                              const float* __restrict__ W1,
                                              const float* __restrict__ b1,
                                              const float* __restrict__ W2,
                                              const float* __restrict__ b2,
                                              const int* __restrict__ cnt,
                                              const int* __restrict__ nbr,
                                              int* __restrict__ fps,
                                              float* __restrict__ agg) {
  __shared__ __align__(16) char smem[SMEM_BYTES];
  const int bid = blockIdx.x, tid = threadIdx.x;

  if (bid < BD) {
    // ================= FPS: one block per graph =================
    float* sP = (float*)(smem + OFF_SP);
    float (*sV)[4] = (float(*)[4])(smem + OFF_SV);
    int   (*sI)[4] = (int(*)[4])(smem + OFF_SI);
    const int g = bid;
    for (int i = tid; i < NPTS * 3; i += 256) sP[i] = pos[(size_t)g * NPTS * 3 + i];
    __syncthreads();

    float px[8], py[8], pz[8], md[8];
#pragma unroll
    for (int j = 0; j < 8; ++j) {
      int p = (j << 8) + tid;
      px[j] = sP[p * 3]; py[j] = sP[p * 3 + 1]; pz[j] = sP[p * 3 + 2];
      md[j] = __builtin_inff();
    }
    int last = 0;
    if (tid == 0) fps[g * MS] = 0;
    for (int s = 1; s < MS; ++s) {
      float lx = sP[last * 3], ly = sP[last * 3 + 1], lz = sP[last * 3 + 2];
      float bv = -1.0f; int bi = NPTS;   // min_d >= 0 always
#pragma unroll
      for (int j = 0; j < 8; ++j) {
        float dx = __fsub_rn(px[j], lx);
        float dy = __fsub_rn(py[j], ly);
        float dz = __fsub_rn(pz[j], lz);
        float d2 = __fadd_rn(__fadd_rn(__fmul_rn(dx, dx), __fmul_rn(dy, dy)),
                             __fmul_rn(dz, dz));
        float m = fminf(md[j], d2);
        md[j] = m;
        int pidx = (j << 8) + tid;
        if (m > bv || (m == bv && pidx < bi)) { bv = m; bi = pidx; }
      }
#pragma unroll
      for (int mk = 32; mk >= 1; mk >>= 1) {     // 64-lane wave reduce
        float ov = __shfl_xor(bv, mk, 64);
        int   oi = __shfl_xor(bi, mk, 64);
        if (ov > bv || (ov == bv && oi < bi)) { bv = ov; bi = oi; }
      }
      const int pb = s & 1;                       // double-buffer -> 1 barrier/step
      if ((tid & 63) == 0) { sV[pb][tid >> 6] = bv; sI[pb][tid >> 6] = bi; }
      __syncthreads();
      bv = sV[pb][0]; bi = sI[pb][0];
#pragma unroll
      for (int w = 1; w < 4; ++w) {
        float ov = sV[pb][w]; int oi = sI[pb][w];
        if (ov > bv || (ov == bv && oi < bi)) { bv = ov; bi = oi; }
      }
      last = bi;
      if (tid == 0) fps[g * MS + s] = last;
    }
    return;
  }

  // ================= edge MLP: 16 points per block =================
  float   (*fT)[36]    = (float(*)[36])(smem + OFF_FT);
  float   (*h1T)[36]   = (float(*)[36])(smem + OFF_H1T);
  unsigned(*aggU)[NH2] = (unsigned(*)[NH2])(smem + OFF_AGG);
  short* epts  = (short*)(smem + OFF_EPTS);
  short* ejs   = (short*)(smem + OFF_EJS);
  int*   starts= (int*)(smem + OFF_STARTS);
  int*   scnt  = (int*)(smem + OFF_SCNT);
  float (*sppos)[3] = (float(*)[3])(smem + OFF_SPPOS);

  const int cb = bid - BD;
  const int p0 = cb << 4;            // first global point of this block
  const int g  = p0 >> 11;
  const int gp = g << 11;            // first point of graph

  if (tid < 16) {
    scnt[tid] = cnt[p0 + tid];
    const float* pp = pos + (size_t)(p0 + tid) * 3;
    sppos[tid][0] = pp[0]; sppos[tid][1] = pp[1]; sppos[tid][2] = pp[2];
  }
  for (int i = tid; i < 16 * NH2; i += 256) ((unsigned*)aggU)[i] = 0u;
  __syncthreads();
  if (tid == 0) {
    int a = 0;
    for (int u = 0; u < 16; ++u) { starts[u] = a; a += scnt[u]; }
    starts[16] = a;
  }
  __syncthreads();
  const int NE  = starts[16];
  const int NEp = (NE + 31) & ~31;
  {
    int u = tid >> 4, su = starts[u], cu = scnt[u];
    for (int k = tid & 15; k < cu; k += 16) {
      epts[su + k] = (short)u;
      ejs [su + k] = (short)nbr[(size_t)(p0 + u) * KNB + k];
    }
    for (int e = NE + tid; e < NEp; e += 256) { epts[e] = 16; ejs[e] = 0; }
  }
  __syncthreads();

  for (int es = 0; es < NEp; es += 32) {
    // ---- stage feats (transposed): 8 threads per edge ----
    {
      int e = tid >> 3, q = tid & 7;
      int ge = es + e;
      int j = ejs[ge];
      const float* xr = x + ((size_t)(gp + j) << 6);
#pragma unroll
      for (int m = 0; m < 2; ++m) {
        int cc = (q << 3) + (m << 2);
        vf4 v = *(const vf4*)(xr + cc);
        fT[cc][e] = v[0]; fT[cc + 1][e] = v[1]; fT[cc + 2][e] = v[2]; fT[cc + 3][e] = v[3];
      }
      if (q == 0) {
        int p = epts[ge]; if (p > 15) p = 15;       // padded edges -> garbage, ignored
        const float* pj = pos + (size_t)(gp + j) * 3;
        fT[64][e] = __fsub_rn(pj[0], sppos[p][0]);
        fT[65][e] = __fsub_rn(pj[1], sppos[p][1]);
        fT[66][e] = __fsub_rn(pj[2], sppos[p][2]);
      }
    }
    __syncthreads();
    // ---- GEMM1: [32,67] x [67,128], thread tile 4 cols x 4 edges ----
    {
      int c0 = (tid & 31) << 2;
      int e0 = (tid >> 5) << 2;
      float acc[4][4];
#pragma unroll
      for (int a = 0; a < 4; ++a)
#pragma unroll
        for (int b = 0; b < 4; ++b) acc[a][b] = 0.f;
      for (int k = 0; k < 67; ++k) {
        vf4 w = *(const vf4*)(W1 + (size_t)k * NH1 + c0);
        vf4 f = *(const vf4*)&fT[k][e0];
#pragma unroll
        for (int a = 0; a < 4; ++a)
#pragma unroll
          for (int b = 0; b < 4; ++b) acc[a][b] += w[a] * f[b];
      }
#pragma unroll
      for (int a = 0; a < 4; ++a) {
        float bias = b1[c0 + a];
        vf4 s;
#pragma unroll
        for (int b = 0; b < 4; ++b) s[b] = fmaxf(acc[a][b] + bias, 0.f);
        *(vf4*)&h1T[c0 + a][e0] = s;
      }
    }
    __syncthreads();
    // ---- GEMM2: [32,128] x [128,256], thread tile 4 cols x 8 edges ----
    {
      int c0 = (tid & 63) << 2;
      int e0 = (tid >> 6) << 3;
      float acc[4][8];
#pragma unroll
      for (int a = 0; a < 4; ++a)
#pragma unroll
        for (int b = 0; b < 8; ++b) acc[a][b] = 0.f;
      for (int k = 0; k < NH1; ++k) {
        vf4 w  = *(const vf4*)(W2 + (size_t)k * NH2 + c0);
        vf4 h0 = *(const vf4*)&h1T[k][e0];
        vf4 h1 = *(const vf4*)&h1T[k][e0 + 4];
#pragma unroll
        for (int a = 0; a < 4; ++a) {
#pragma unroll
          for (int b = 0; b < 4; ++b) {
            acc[a][b]     += w[a] * h0[b];
            acc[a][b + 4] += w[a] * h1[b];
          }
        }
      }
      float bias[4] = { b2[c0], b2[c0 + 1], b2[c0 + 2], b2[c0 + 3] };
      int rp = -1; float rm[4] = {0, 0, 0, 0};
#pragma unroll
      for (int ee = 0; ee < 8; ++ee) {
        int p = epts[es + e0 + ee];
        float v[4];
#pragma unroll
        for (int a = 0; a < 4; ++a) v[a] = fmaxf(acc[a][ee] + bias[a], 0.f);
        if (p != rp) {
          if (rp >= 0 && rp < 16) {
#pragma unroll
            for (int a = 0; a < 4; ++a)
              atomicMax(&aggU[rp][c0 + a], __float_as_uint(rm[a]));
          }
          rp = p;
#pragma unroll
          for (int a = 0; a < 4; ++a) rm[a] = v[a];
        } else {
#pragma unroll
          for (int a = 0; a < 4; ++a) rm[a] = fmaxf(rm[a], v[a]);
        }
      }
      if (rp >= 0 && rp < 16) {
#pragma unroll
        for (int a = 0; a < 4; ++a)
          atomicMax(&aggU[rp][c0 + a], __float_as_uint(rm[a]));
      }
    }
    __syncthreads();
  }
  // ---- write agg (zeros stay zero for isolated points == PyG semantics) ----
  for (int i = tid; i < 16 * NH2; i += 256) {
    int p = i >> 8, cc = i & 255;
    agg[(size_t)(p0 + p) * NH2 + cc] = __uint_as_float(aggU[p][cc]);
  }
}

// =====================================================================
// k_out: x_all = agg @ Wg + bg   (16384x256 @ 256x256), 64x64 tiles
// =====================================================================
__global__ __launch_bounds__(256) void k_out(const float* __restrict__ agg,
                                             const float* __restrict__ Wg,
                                             const float* __restrict__ bg,
                                             float* __restrict__ out) {
  __shared__ float At[16][68];   // [k][row], padded
  __shared__ float Bt[16][64];   // [k][col]
  const int bid = blockIdx.x, tid = threadIdx.x;
  const int r0  = (bid >> 2) << 6;
  const int c0b = (bid & 3) << 6;
  const int tr = tid >> 4, tc = tid & 15;
  float acc[4][4];
#pragma unroll
  for (int i = 0; i < 4; ++i)
#pragma unroll
    for (int j = 0; j < 4; ++j) acc[i][j] = 0.f;

  for (int k0 = 0; k0 < NH2; k0 += 16) {
    {
      int rr = tid >> 2, k4 = (tid & 3) << 2;
      vf4 v = *(const vf4*)(agg + (size_t)(r0 + rr) * NH2 + k0 + k4);
      At[k4][rr] = v[0]; At[k4 + 1][rr] = v[1]; At[k4 + 2][rr] = v[2]; At[k4 + 3][rr] = v[3];
      int kk = tid >> 4, c4 = (tid & 15) << 2;
      *(vf4*)&Bt[kk][c4] = *(const vf4*)(Wg + (size_t)(k0 + kk) * NH2 + c0b + c4);
    }
    __syncthreads();
#pragma unroll
    for (int kk = 0; kk < 16; ++kk) {
      vf4 a = *(const vf4*)&At[kk][tr << 2];
      vf4 b = *(const vf4*)&Bt[kk][tc << 2];
#pragma unroll
      for (int i = 0; i < 4; ++i)
#pragma unroll
        for (int j = 0; j < 4; ++j) acc[i][j] += a[i] * b[j];
    }
    __syncthreads();
  }
#pragma unroll
  for (int i = 0; i < 4; ++i) {
    vf4 o;
#pragma unroll
    for (int j = 0; j < 4; ++j) o[j] = acc[i][j] + bg[c0b + (tc << 2) + j];
    *(vf4*)(out + (size_t)(r0 + (tr << 2) + i) * NH2 + c0b + (tc << 2)) = o;
  }
}

// =====================================================================
// k_gather: x_dst / pos_dst / batch_dst from fps indices
// =====================================================================
__global__ __launch_bounds__(64) void k_gather(const float* __restrict__ pos,
                                               const int* __restrict__ fps,
                                               float* __restrict__ out) {
  const int s = blockIdx.x, t = threadIdx.x;
  const int g = s >> 9;
  const int idx = fps[s];
  const int row = (g << 11) + idx;
  const vf4* src = (const vf4*)(out + (size_t)row * NH2);
  vf4* dst = (vf4*)(out + XD_OFF + (size_t)s * NH2);
  dst[t] = src[t];
  if (t == 0) {
    const float* pr = pos + (size_t)row * 3;
    out[PD_OFF + s * 3]     = pr[0];
    out[PD_OFF + s * 3 + 1] = pr[1];
    out[PD_OFF + s * 3 + 2] = pr[2];
    out[BT_OFF + s] = (float)g;
  }
}

// =====================================================================
extern "C" void kernel_launch(void* const* d_in, const int* in_sizes, int n_in,
                              void* d_out, int out_size, void* d_ws, size_t ws_size,
                              hipStream_t stream) {
  const float* x   = (const float*)d_in[0];
  const float* pos = (const float*)d_in[1];
  // d_in[2] = batch (int32) — derivable, unused
  const float* W1 = (const float*)d_in[3];
  const float* b1 = (const float*)d_in[4];
  const float* W2 = (const float*)d_in[5];
  const float* b2 = (const float*)d_in[6];
  const float* Wg = (const float*)d_in[7];
  const float* bg = (const float*)d_in[8];
  float* out = (float*)d_out;

  char* ws = (char*)d_ws;
  int*   fps  = (int*)(ws);                 //   4096 ints
  int*   cnt  = (int*)(ws + 16384);         //  16384 ints
  int*   nbr  = (int*)(ws + 81920);         //  16384*32 ints (2 MB)
  float* nbrd = (float*)(ws + 2179072);     //  16384*32 floats (2 MB)
  float* agg  = (float*)(ws + 4276224);     //  16384*256 floats (16 MB)

  hipLaunchKernelGGL(k_radius, dim3(64),     dim3(256), 0, stream, pos, cnt, nbr, nbrd);
  hipLaunchKernelGGL(k_conv,   dim3(BD+1024),dim3(256), 0, stream, x, pos, W1, b1, W2, b2, cnt, nbr, fps, agg);
  hipLaunchKernelGGL(k_out,    dim3(1024),   dim3(256), 0, stream, agg, Wg, bg, out);
  hipLaunchKernelGGL(k_gather, dim3(BD*MS),  dim3(64),  0, stream, pos, fps, out);
}

// Round 3
// 650.742 us; speedup vs baseline: 1.5140x; 1.5140x over previous
//
#include <hip/hip_runtime.h>

// ---- problem constants ----
#define BD    8
#define NPTS  2048
#define FIN   64
#define KNB   32
#define MS    512          // fps samples per graph
#define NH1   128
#define NH2   256
#define NTOT  (BD*NPTS)    // 16384
#define R2F   ((float)(0.1*0.1))

// output layout (floats)
#define XALL_N   (NTOT*NH2)            // 4194304
#define XD_OFF   XALL_N                // x_dst
#define PD_OFF   (XD_OFF + BD*MS*NH2)  // 5242880 pos_dst
#define BT_OFF   (PD_OFF + BD*MS*3)    // 5255168 batch_dst

typedef __attribute__((ext_vector_type(4))) float vf4;
typedef unsigned long long ull;

// =====================================================================
// k_radius: 64 blocks x 256 thr; per-point <=32 nearest within r
// unrolled x8: batch LDS broadcast reads ahead of the distance math
// =====================================================================
__global__ __launch_bounds__(256) void k_radius(const float* __restrict__ pos,
                                                int* __restrict__ cnt,
                                                int* __restrict__ nbr,
                                                float* __restrict__ nbrd) {
  __shared__ float sP[NPTS * 3];
  const int bid = blockIdx.x, tid = threadIdx.x;
  const int g  = bid >> 3;
  const int ch = bid & 7;
  for (int i = tid; i < NPTS * 3; i += 256) sP[i] = pos[(size_t)g * NPTS * 3 + i];
  __syncthreads();

  const int iL = (ch << 8) + tid;            // graph-local point
  const float mx = sP[iL * 3], my = sP[iL * 3 + 1], mz = sP[iL * 3 + 2];
  const int gi = g * NPTS + iL;
  const long base = (long)gi * KNB;
  int c = 0;
  for (int j0 = 0; j0 < NPTS; j0 += 8) {
    float d2a[8];
#pragma unroll
    for (int u = 0; u < 8; ++u) {
      float qx = sP[(j0 + u) * 3];
      float qy = sP[(j0 + u) * 3 + 1];
      float qz = sP[(j0 + u) * 3 + 2];
      float dx = __fsub_rn(qx, mx);
      float dy = __fsub_rn(qy, my);
      float dz = __fsub_rn(qz, mz);
      d2a[u] = __fadd_rn(__fadd_rn(__fmul_rn(dx, dx), __fmul_rn(dy, dy)),
                         __fmul_rn(dz, dz));
    }
#pragma unroll
    for (int u = 0; u < 8; ++u) {
      int j = j0 + u;
      float d2 = d2a[u];
      if (d2 <= R2F && j != iL) {
        if (c < KNB) {
          nbr[base + c] = j; nbrd[base + c] = d2; ++c;
        } else {                                   // rare: keep 32 smallest
          int mk = 0; float mv = nbrd[base];
          for (int k2 = 1; k2 < KNB; ++k2) {
            float v = nbrd[base + k2];
            if (v > mv) { mv = v; mk = k2; }
          }
          if (d2 < mv) { nbr[base + mk] = j; nbrd[base + mk] = d2; }
        }
      }
    }
  }
  cnt[gi] = c;
}

// =====================================================================
// k_conv: blocks 0..7 = FPS (overlapped); blocks 8..1031 = edge MLP
// =====================================================================
#define SMEM_BYTES 46848
// conv-role layout (16B-aligned sections)
#define OFF_FT     0        // float [67][36]  = 9648
#define OFF_H1T    9648     // float [128][36] = 18432
#define OFF_AGG    28080    // uint  [16][256] = 16384
#define OFF_EPTS   44464    // short [512]     = 1024
#define OFF_EJS    45488    // short [512]     = 1024
#define OFF_STARTS 46512    // int   [17]      = 68
#define OFF_SCNT   46580    // int   [16]      = 64
#define OFF_SPPOS  46644    // float [16][3]   = 192  -> ends 46836
// fps-role: record slots [2 buf][4 wave][8 floats] = 256 B at offset 0

struct Cand { ull k; float x, y, z; };

__device__ __forceinline__ void mrg(Cand& a, const Cand& b) {
  bool t = b.k > a.k;          // u64 compare: larger (val, ~idx) wins
  a.k = t ? b.k : a.k;
  a.x = t ? b.x : a.x;
  a.y = t ? b.y : a.y;
  a.z = t ? b.z : a.z;
}

__global__ __launch_bounds__(256) void k_conv(const float* __restrict__ x,
                                              const float* __restrict__ pos,
                                              const float* __restrict__ W1,
                                              const float* __restrict__ b1,
                                              const float* __restrict__ W2,
                                              const float* __restrict__ b2,
                                              const int* __restrict__ cnt,
                                              const int* __restrict__ nbr,
                                              int* __restrict__ fps,
                                              float* __restrict__ agg) {
  __shared__ __align__(16) char smem[SMEM_BYTES];
  const int bid = blockIdx.x, tid = threadIdx.x;

  if (bid < BD) {
    // ================= FPS: one block per graph, 8 pts/lane =================
    __builtin_amdgcn_s_setprio(1);     // FPS is the serial critical path
    const int g = bid;
    float (*rec)[4][8] = (float(*)[4][8])smem;   // [buf][wave][8]
    const int wv = tid >> 6, ln = tid & 63;

    float px[8], py[8], pz[8], md[8];
#pragma unroll
    for (int j = 0; j < 8; ++j) {
      int p = (j << 8) + tid;
      const float* pp = pos + ((size_t)g * NPTS + p) * 3;
      px[j] = pp[0]; py[j] = pp[1]; pz[j] = pp[2];
      md[j] = __builtin_inff();
    }
    // center 0 = point 0
    float lx = pos[(size_t)g * NPTS * 3];
    float ly = pos[(size_t)g * NPTS * 3 + 1];
    float lz = pos[(size_t)g * NPTS * 3 + 2];
    if (tid == 0) fps[g * MS] = 0;
    const unsigned ntid = ~(unsigned)tid;

    for (int s = 1; s < MS; ++s) {
      Cand c[8];
#pragma unroll
      for (int j = 0; j < 8; ++j) {
        float dx = __fsub_rn(px[j], lx);
        float dy = __fsub_rn(py[j], ly);
        float dz = __fsub_rn(pz[j], lz);
        float d2 = __fadd_rn(__fadd_rn(__fmul_rn(dx, dx), __fmul_rn(dy, dy)),
                             __fmul_rn(dz, dz));
        float m = fminf(md[j], d2);
        md[j] = m;
        // key = (value_bits << 32) | ~p  -> max key == first argmax
        c[j].k = ((ull)__float_as_uint(m) << 32) | (unsigned)(ntid - (j << 8));
        c[j].x = px[j]; c[j].y = py[j]; c[j].z = pz[j];
      }
      // local 8 -> 1 tree
      mrg(c[0], c[4]); mrg(c[1], c[5]); mrg(c[2], c[6]); mrg(c[3], c[7]);
      mrg(c[0], c[2]); mrg(c[1], c[3]);
      mrg(c[0], c[1]);
      // 64-lane butterfly (carries winner xyz; all lanes converge)
      Cand w = c[0];
#pragma unroll
      for (int mk = 32; mk >= 1; mk >>= 1) {
        Cand o;
        o.k = __shfl_xor(w.k, mk, 64);
        o.x = __shfl_xor(w.x, mk, 64);
        o.y = __shfl_xor(w.y, mk, 64);
        o.z = __shfl_xor(w.z, mk, 64);
        mrg(w, o);
      }
      const int pb = s & 1;
      if (ln == 0) {
        float* r = rec[pb][wv];
        r[0] = __uint_as_float((unsigned)(w.k >> 32));
        r[1] = __uint_as_float((unsigned)w.k);
        r[2] = w.x; r[3] = w.y; r[4] = w.z;
      }
      __syncthreads();
      // merge the 4 wave records (broadcast reads)
      Cand f;
      {
        const float* r0 = rec[pb][0];
        f.k = ((ull)__float_as_uint(r0[0]) << 32) | __float_as_uint(r0[1]);
        f.x = r0[2]; f.y = r0[3]; f.z = r0[4];
      }
#pragma unroll
      for (int wq = 1; wq < 4; ++wq) {
        const float* rq = rec[pb][wq];
        Cand o;
        o.k = ((ull)__float_as_uint(rq[0]) << 32) | __float_as_uint(rq[1]);
        o.x = rq[2]; o.y = rq[3]; o.z = rq[4];
        mrg(f, o);
      }
      lx = f.x; ly = f.y; lz = f.z;
      if (tid == 0) fps[g * MS + s] = (int)(~(unsigned)f.k);
    }
    return;
  }

  // ================= edge MLP: 16 points per block =================
  float   (*fT)[36]    = (float(*)[36])(smem + OFF_FT);
  float   (*h1T)[36]   = (float(*)[36])(smem + OFF_H1T);
  unsigned(*aggU)[NH2] = (unsigned(*)[NH2])(smem + OFF_AGG);
  short* epts  = (short*)(smem + OFF_EPTS);
  short* ejs   = (short*)(smem + OFF_EJS);
  int*   starts= (int*)(smem + OFF_STARTS);
  int*   scnt  = (int*)(smem + OFF_SCNT);
  float (*sppos)[3] = (float(*)[3])(smem + OFF_SPPOS);

  const int cb = bid - BD;
  const int p0 = cb << 4;            // first global point of this block
  const int g  = p0 >> 11;
  const int gp = g << 11;            // first point of graph

  if (tid < 16) {
    scnt[tid] = cnt[p0 + tid];
    const float* pp = pos + (size_t)(p0 + tid) * 3;
    sppos[tid][0] = pp[0]; sppos[tid][1] = pp[1]; sppos[tid][2] = pp[2];
  }
  for (int i = tid; i < 16 * NH2; i += 256) ((unsigned*)aggU)[i] = 0u;
  __syncthreads();
  if (tid == 0) {
    int a = 0;
    for (int u = 0; u < 16; ++u) { starts[u] = a; a += scnt[u]; }
    starts[16] = a;
  }
  __syncthreads();
  const int NE  = starts[16];
  const int NEp = (NE + 31) & ~31;
  {
    int u = tid >> 4, su = starts[u], cu = scnt[u];
    for (int k = tid & 15; k < cu; k += 16) {
      epts[su + k] = (short)u;
      ejs [su + k] = (short)nbr[(size_t)(p0 + u) * KNB + k];
    }
    for (int e = NE + tid; e < NEp; e += 256) { epts[e] = 16; ejs[e] = 0; }
  }
  __syncthreads();

  for (int es = 0; es < NEp; es += 32) {
    // ---- stage feats (transposed): 8 threads per edge ----
    {
      int e = tid >> 3, q = tid & 7;
      int ge = es + e;
      int j = ejs[ge];
      const float* xr = x + ((size_t)(gp + j) << 6);
#pragma unroll
      for (int m = 0; m < 2; ++m) {
        int cc = (q << 3) + (m << 2);
        vf4 v = *(const vf4*)(xr + cc);
        fT[cc][e] = v[0]; fT[cc + 1][e] = v[1]; fT[cc + 2][e] = v[2]; fT[cc + 3][e] = v[3];
      }
      if (q == 0) {
        int p = epts[ge]; if (p > 15) p = 15;       // padded edges -> garbage, ignored
        const float* pj = pos + (size_t)(gp + j) * 3;
        fT[64][e] = __fsub_rn(pj[0], sppos[p][0]);
        fT[65][e] = __fsub_rn(pj[1], sppos[p][1]);
        fT[66][e] = __fsub_rn(pj[2], sppos[p][2]);
      }
    }
    __syncthreads();
    // ---- GEMM1: [32,67] x [67,128], thread tile 4 cols x 4 edges ----
    {
      int c0 = (tid & 31) << 2;
      int e0 = (tid >> 5) << 2;
      float acc[4][4];
#pragma unroll
      for (int a = 0; a < 4; ++a)
#pragma unroll
        for (int b = 0; b < 4; ++b) acc[a][b] = 0.f;
      for (int k = 0; k < 67; ++k) {
        vf4 w = *(const vf4*)(W1 + (size_t)k * NH1 + c0);
        vf4 f = *(const vf4*)&fT[k][e0];
#pragma unroll
        for (int a = 0; a < 4; ++a)
#pragma unroll
          for (int b = 0; b < 4; ++b) acc[a][b] += w[a] * f[b];
      }
#pragma unroll
      for (int a = 0; a < 4; ++a) {
        float bias = b1[c0 + a];
        vf4 s;
#pragma unroll
        for (int b = 0; b < 4; ++b) s[b] = fmaxf(acc[a][b] + bias, 0.f);
        *(vf4*)&h1T[c0 + a][e0] = s;
      }
    }
    __syncthreads();
    // ---- GEMM2: [32,128] x [128,256], thread tile 4 cols x 8 edges ----
    {
      int c0 = (tid & 63) << 2;
      int e0 = (tid >> 6) << 3;
      float acc[4][8];
#pragma unroll
      for (int a = 0; a < 4; ++a)
#pragma unroll
        for (int b = 0; b < 8; ++b) acc[a][b] = 0.f;
      for (int k = 0; k < NH1; ++k) {
        vf4 w  = *(const vf4*)(W2 + (size_t)k * NH2 + c0);
        vf4 h0 = *(const vf4*)&h1T[k][e0];
        vf4 h1 = *(const vf4*)&h1T[k][e0 + 4];
#pragma unroll
        for (int a = 0; a < 4; ++a) {
#pragma unroll
          for (int b = 0; b < 4; ++b) {
            acc[a][b]     += w[a] * h0[b];
            acc[a][b + 4] += w[a] * h1[b];
          }
        }
      }
      float bias[4] = { b2[c0], b2[c0 + 1], b2[c0 + 2], b2[c0 + 3] };
      int rp = -1; float rm[4] = {0, 0, 0, 0};
#pragma unroll
      for (int ee = 0; ee < 8; ++ee) {
        int p = epts[es + e0 + ee];
        float v[4];
#pragma unroll
        for (int a = 0; a < 4; ++a) v[a] = fmaxf(acc[a][ee] + bias[a], 0.f);
        if (p != rp) {
          if (rp >= 0 && rp < 16) {
#pragma unroll
            for (int a = 0; a < 4; ++a)
              atomicMax(&aggU[rp][c0 + a], __float_as_uint(rm[a]));
          }
          rp = p;
#pragma unroll
          for (int a = 0; a < 4; ++a) rm[a] = v[a];
        } else {
#pragma unroll
          for (int a = 0; a < 4; ++a) rm[a] = fmaxf(rm[a], v[a]);
        }
      }
      if (rp >= 0 && rp < 16) {
#pragma unroll
        for (int a = 0; a < 4; ++a)
          atomicMax(&aggU[rp][c0 + a], __float_as_uint(rm[a]));
      }
    }
    __syncthreads();
  }
  // ---- write agg (zeros stay zero for isolated points == PyG semantics) ----
  for (int i = tid; i < 16 * NH2; i += 256) {
    int p = i >> 8, cc = i & 255;
    agg[(size_t)(p0 + p) * NH2 + cc] = __uint_as_float(aggU[p][cc]);
  }
}

// =====================================================================
// k_out: x_all = agg @ Wg + bg   (16384x256 @ 256x256), 64x64 tiles
// =====================================================================
__global__ __launch_bounds__(256) void k_out(const float* __restrict__ agg,
                                             const float* __restrict__ Wg,
                                             const float* __restrict__ bg,
                                             float* __restrict__ out) {
  __shared__ float At[16][68];   // [k][row], padded
  __shared__ float Bt[16][64];   // [k][col]
  const int bid = blockIdx.x, tid = threadIdx.x;
  const int r0  = (bid >> 2) << 6;
  const int c0b = (bid & 3) << 6;
  const int tr = tid >> 4, tc = tid & 15;
  float acc[4][4];
#pragma unroll
  for (int i = 0; i < 4; ++i)
#pragma unroll
    for (int j = 0; j < 4; ++j) acc[i][j] = 0.f;

  for (int k0 = 0; k0 < NH2; k0 += 16) {
    {
      int rr = tid >> 2, k4 = (tid & 3) << 2;
      vf4 v = *(const vf4*)(agg + (size_t)(r0 + rr) * NH2 + k0 + k4);
      At[k4][rr] = v[0]; At[k4 + 1][rr] = v[1]; At[k4 + 2][rr] = v[2]; At[k4 + 3][rr] = v[3];
      int kk = tid >> 4, c4 = (tid & 15) << 2;
      *(vf4*)&Bt[kk][c4] = *(const vf4*)(Wg + (size_t)(k0 + kk) * NH2 + c0b + c4);
    }
    __syncthreads();
#pragma unroll
    for (int kk = 0; kk < 16; ++kk) {
      vf4 a = *(const vf4*)&At[kk][tr << 2];
      vf4 b = *(const vf4*)&Bt[kk][tc << 2];
#pragma unroll
      for (int i = 0; i < 4; ++i)
#pragma unroll
        for (int j = 0; j < 4; ++j) acc[i][j] += a[i] * b[j];
    }
    __syncthreads();
  }
#pragma unroll
  for (int i = 0; i < 4; ++i) {
    vf4 o;
#pragma unroll
    for (int j = 0; j < 4; ++j) o[j] = acc[i][j] + bg[c0b + (tc << 2) + j];
    *(vf4*)(out + (size_t)(r0 + (tr << 2) + i) * NH2 + c0b + (tc << 2)) = o;
  }
}

// =====================================================================
// k_gather: x_dst / pos_dst / batch_dst from fps indices
// =====================================================================
__global__ __launch_bounds__(64) void k_gather(const float* __restrict__ pos,
                                               const int* __restrict__ fps,
                                               float* __restrict__ out) {
  const int s = blockIdx.x, t = threadIdx.x;
  const int g = s >> 9;
  const int idx = fps[s];
  const int row = (g << 11) + idx;
  const vf4* src = (const vf4*)(out + (size_t)row * NH2);
  vf4* dst = (vf4*)(out + XD_OFF + (size_t)s * NH2);
  dst[t] = src[t];
  if (t == 0) {
    const float* pr = pos + (size_t)row * 3;
    out[PD_OFF + s * 3]     = pr[0];
    out[PD_OFF + s * 3 + 1] = pr[1];
    out[PD_OFF + s * 3 + 2] = pr[2];
    out[BT_OFF + s] = (float)g;
  }
}

// =====================================================================
extern "C" void kernel_launch(void* const* d_in, const int* in_sizes, int n_in,
                              void* d_out, int out_size, void* d_ws, size_t ws_size,
                              hipStream_t stream) {
  const float* x   = (const float*)d_in[0];
  const float* pos = (const float*)d_in[1];
  // d_in[2] = batch (int32) — derivable, unused
  const float* W1 = (const float*)d_in[3];
  const float* b1 = (const float*)d_in[4];
  const float* W2 = (const float*)d_in[5];
  const float* b2 = (const float*)d_in[6];
  const float* Wg = (const float*)d_in[7];
  const float* bg = (const float*)d_in[8];
  float* out = (float*)d_out;

  char* ws = (char*)d_ws;
  int*   fps  = (int*)(ws);                 //   4096 ints
  int*   cnt  = (int*)(ws + 16384);         //  16384 ints
  int*   nbr  = (int*)(ws + 81920);         //  16384*32 ints (2 MB)
  float* nbrd = (float*)(ws + 2179072);     //  16384*32 floats (2 MB)
  float* agg  = (float*)(ws + 4276224);     //  16384*256 floats (16 MB)

  hipLaunchKernelGGL(k_radius, dim3(64),     dim3(256), 0, stream, pos, cnt, nbr, nbrd);
  hipLaunchKernelGGL(k_conv,   dim3(BD+1024),dim3(256), 0, stream, x, pos, W1, b1, W2, b2, cnt, nbr, fps, agg);
  hipLaunchKernelGGL(k_out,    dim3(1024),   dim3(256), 0, stream, agg, Wg, bg, out);
  hipLaunchKernelGGL(k_gather, dim3(BD*MS),  dim3(64),  0, stream, pos, fps, out);
}

// Round 7
// 391.818 us; speedup vs baseline: 2.5145x; 1.6608x over previous
//
#include <hip/hip_runtime.h>

// ---- problem constants ----
#define BD    8
#define NPTS  2048
#define FIN   64
#define KNB   32
#define MS    512          // fps samples per graph
#define NH1   128
#define NH2   256
#define NTOT  (BD*NPTS)    // 16384
#define R2F   ((float)(0.1*0.1))

// output layout (floats)
#define XALL_N   (NTOT*NH2)            // 4194304
#define XD_OFF   XALL_N                // x_dst
#define PD_OFF   (XD_OFF + BD*MS*NH2)  // 5242880 pos_dst
#define BT_OFF   (PD_OFF + BD*MS*3)    // 5255168 batch_dst

typedef __attribute__((ext_vector_type(4))) float vf4;
typedef unsigned long long ull;

// =====================================================================
// k_conv: blocks 0..7 = FPS; blocks 8..1031 = in-block radius + edge MLP
// =====================================================================
#define SMEM_BYTES 47872
// conv-role layout (16B-aligned sections)
#define OFF_FT     0        // float [67][36]  = 9648
#define OFF_H1T    9648     // float [128][36] = 18432
#define OFF_AGG    28080    // uint  [16][256] = 16384
#define OFF_EPTS   44464    // short [512]     = 1024
#define OFF_EJS    45488    // short [512]     = 1024
#define OFF_NBR16  46512    // short [16][32]  = 1024
#define OFF_STARTS 47536    // int   [17]      = 68 (pad to 47616)
#define OFF_LCNT   47616    // int   [16]      = 64
#define OFF_SPPOS  47680    // float [16][3]   = 192 -> 47872
// fps-role layout
#define OFF_SPX    0        // float[2048] x
#define OFF_SPY    8192     // float[2048] y
#define OFF_SPZ    16384    // float[2048] z
#define OFF_REC    24576    // ull [2][4]

// one DPP reduce level on (hi,lo) u64 key: take other if other > mine
#define DPP_STEP(CTRL, RM)                                                      \
  {                                                                             \
    unsigned oh = (unsigned)__builtin_amdgcn_update_dpp(0, (int)hi, CTRL, RM, 0xF, true); \
    unsigned ol = (unsigned)__builtin_amdgcn_update_dpp(0, (int)lo, CTRL, RM, 0xF, true); \
    bool t = (oh > hi) || (oh == hi && ol > lo);                                \
    hi = t ? oh : hi; lo = t ? ol : lo;                                         \
  }

__global__ __launch_bounds__(256) void k_conv(const float* __restrict__ x,
                                              const float* __restrict__ pos,
                                              const float* __restrict__ W1,
                                              const float* __restrict__ b1,
                                              const float* __restrict__ W2,
                                              const float* __restrict__ b2,
                                              int* __restrict__ fps,
                                              float* __restrict__ agg) {
  __shared__ __align__(16) char smem[SMEM_BYTES];
  const int bid = blockIdx.x, tid = threadIdx.x;

  if (bid < BD) {
    // ================= FPS: one block per graph, 8 pts/lane =================
    __builtin_amdgcn_s_setprio(1);     // FPS is the serial critical path
    const int g = bid;
    float* sPx = (float*)(smem + OFF_SPX);
    float* sPy = (float*)(smem + OFF_SPY);
    float* sPz = (float*)(smem + OFF_SPZ);
    ull (*rec)[4] = (ull(*)[4])(smem + OFF_REC);
    const float* pg = pos + (size_t)g * NPTS * 3;

    // load 8 consecutive points (96B) via 6 vf4 loads; keep in regs + LDS SoA
    float px[8], py[8], pz[8], md[8];
    {
      const vf4* src = (const vf4*)(pg + tid * 24);
      vf4 a0 = src[0], a1 = src[1], a2 = src[2], a3 = src[3], a4 = src[4], a5 = src[5];
      px[0]=a0[0]; py[0]=a0[1]; pz[0]=a0[2];
      px[1]=a0[3]; py[1]=a1[0]; pz[1]=a1[1];
      px[2]=a1[2]; py[2]=a1[3]; pz[2]=a2[0];
      px[3]=a2[1]; py[3]=a2[2]; pz[3]=a2[3];
      px[4]=a3[0]; py[4]=a3[1]; pz[4]=a3[2];
      px[5]=a3[3]; py[5]=a4[0]; pz[5]=a4[1];
      px[6]=a4[2]; py[6]=a4[3]; pz[6]=a5[0];
      px[7]=a5[1]; py[7]=a5[2]; pz[7]=a5[3];
      vf4 w0, w1;
      w0[0]=px[0];w0[1]=px[1];w0[2]=px[2];w0[3]=px[3];
      w1[0]=px[4];w1[1]=px[5];w1[2]=px[6];w1[3]=px[7];
      *(vf4*)(sPx + tid*8) = w0; *(vf4*)(sPx + tid*8 + 4) = w1;
      w0[0]=py[0];w0[1]=py[1];w0[2]=py[2];w0[3]=py[3];
      w1[0]=py[4];w1[1]=py[5];w1[2]=py[6];w1[3]=py[7];
      *(vf4*)(sPy + tid*8) = w0; *(vf4*)(sPy + tid*8 + 4) = w1;
      w0[0]=pz[0];w0[1]=pz[1];w0[2]=pz[2];w0[3]=pz[3];
      w1[0]=pz[4];w1[1]=pz[5];w1[2]=pz[6];w1[3]=pz[7];
      *(vf4*)(sPz + tid*8) = w0; *(vf4*)(sPz + tid*8 + 4) = w1;
    }
    unsigned klo[8];
#pragma unroll
    for (int u = 0; u < 8; ++u) { md[u] = __builtin_inff(); klo[u] = ~(unsigned)(tid*8 + u); }
    __syncthreads();
    float lx = sPx[0], ly = sPy[0], lz = sPz[0];
    if (tid == 0) fps[g * MS] = 0;

    for (int s = 1; s < MS; ++s) {
      ull best = 0;
#pragma unroll
      for (int u = 0; u < 8; ++u) {
        float dx = __fsub_rn(px[u], lx);
        float dy = __fsub_rn(py[u], ly);
        float dz = __fsub_rn(pz[u], lz);
        float d2 = __fadd_rn(__fadd_rn(__fmul_rn(dx, dx), __fmul_rn(dy, dy)),
                             __fmul_rn(dz, dz));
        float m = fminf(md[u], d2);
        md[u] = m;
        ull k = ((ull)__float_as_uint(m) << 32) | klo[u];
        best = (k > best) ? k : best;
      }
      unsigned hi = (unsigned)(best >> 32), lo = (unsigned)best;
      DPP_STEP(0x111, 0xF)   // row_shr:1
      DPP_STEP(0x112, 0xF)   // row_shr:2
      DPP_STEP(0x114, 0xF)   // row_shr:4
      DPP_STEP(0x118, 0xF)   // row_shr:8  -> lane15 of each row has row-reduce
      DPP_STEP(0x142, 0xA)   // row_bcast:15 -> lane31/63 combine halves
      DPP_STEP(0x143, 0xC)   // row_bcast:31 -> lane63 has wave reduce
      const int pb = s & 1;
      if ((tid & 63) == 63) rec[pb][tid >> 6] = ((ull)hi << 32) | lo;
      __syncthreads();
      ull f = rec[pb][0];
      ull f1 = rec[pb][1]; if (f1 > f) f = f1;
      ull f2 = rec[pb][2]; if (f2 > f) f = f2;
      ull f3 = rec[pb][3]; if (f3 > f) f = f3;
      unsigned p = ~(unsigned)f;          // winner point index
      lx = sPx[p]; ly = sPy[p]; lz = sPz[p];
      if (tid == 0) fps[g * MS + s] = (int)p;
    }
    return;
  }

  // ================= conv block: 16 points =================
  float   (*fT)[36]    = (float(*)[36])(smem + OFF_FT);
  float   (*h1T)[36]   = (float(*)[36])(smem + OFF_H1T);
  unsigned(*aggU)[NH2] = (unsigned(*)[NH2])(smem + OFF_AGG);
  short* epts   = (short*)(smem + OFF_EPTS);
  short* ejs    = (short*)(smem + OFF_EJS);
  short* nbr16  = (short*)(smem + OFF_NBR16);   // [16][KNB]
  int*   starts = (int*)(smem + OFF_STARTS);
  int*   lcnt   = (int*)(smem + OFF_LCNT);
  float (*sppos)[3] = (float(*)[3])(smem + OFF_SPPOS);

  const int cb  = bid - BD;
  const int p0  = cb << 4;           // first global point of this block
  const int g   = p0 >> 11;
  const int gp  = g << 11;           // first point of graph
  const int p0l = p0 & (NPTS - 1);   // graph-local base
  const float* pg0 = pos + (size_t)g * NPTS * 3;

  if (tid < 16) {
    lcnt[tid] = 0;
    const float* pp = pg0 + (size_t)(p0l + tid) * 3;
    sppos[tid][0] = pp[0]; sppos[tid][1] = pp[1]; sppos[tid][2] = pp[2];
  }
  for (int i = tid; i < 16 * NH2; i += 256) ((unsigned*)aggU)[i] = 0u;
  __syncthreads();

  // ---- phase 1: in-block radius search; thread owns 8 source points ----
  {
    float jx[8], jy[8], jz[8];
    const vf4* src = (const vf4*)(pg0 + tid * 24);
    vf4 a0 = src[0], a1 = src[1], a2 = src[2], a3 = src[3], a4 = src[4], a5 = src[5];
    jx[0]=a0[0]; jy[0]=a0[1]; jz[0]=a0[2];
    jx[1]=a0[3]; jy[1]=a1[0]; jz[1]=a1[1];
    jx[2]=a1[2]; jy[2]=a1[3]; jz[2]=a2[0];
    jx[3]=a2[1]; jy[3]=a2[2]; jz[3]=a2[3];
    jx[4]=a3[0]; jy[4]=a3[1]; jz[4]=a3[2];
    jx[5]=a3[3]; jy[5]=a4[0]; jz[5]=a4[1];
    jx[6]=a4[2]; jy[6]=a4[3]; jz[6]=a5[0];
    jx[7]=a5[1]; jy[7]=a5[2]; jz[7]=a5[3];
    const int j0 = tid * 8;
#pragma unroll
    for (int p = 0; p < 16; ++p) {
      float tx = sppos[p][0], ty = sppos[p][1], tz = sppos[p][2];
      const int self = p0l + p;
#pragma unroll
      for (int u = 0; u < 8; ++u) {
        float dx = __fsub_rn(jx[u], tx);
        float dy = __fsub_rn(jy[u], ty);
        float dz = __fsub_rn(jz[u], tz);
        float d2 = __fadd_rn(__fadd_rn(__fmul_rn(dx, dx), __fmul_rn(dy, dy)),
                             __fmul_rn(dz, dz));
        if (d2 <= R2F && (j0 + u) != self) {
          int slot = atomicAdd(&lcnt[p], 1);
          if (slot < KNB) nbr16[p * KNB + slot] = (short)(j0 + u);
        }
      }
    }
  }
  __syncthreads();
  // ---- overflow fallback (astronomically rare): exact 32-smallest ----
  if (tid < 16) {
    int c = lcnt[tid];
    if (c > KNB) {
      float* dd = ((float*)fT) + tid * KNB;   // scratch (fT unused yet)
      short* jj = nbr16 + tid * KNB;
      int cc = 0;
      const int self = p0l + tid;
      const float tx = sppos[tid][0], ty = sppos[tid][1], tz = sppos[tid][2];
      for (int j = 0; j < NPTS; ++j) {
        const float* pj = pg0 + (size_t)j * 3;
        float dx = __fsub_rn(pj[0], tx);
        float dy = __fsub_rn(pj[1], ty);
        float dz = __fsub_rn(pj[2], tz);
        float d2 = __fadd_rn(__fadd_rn(__fmul_rn(dx, dx), __fmul_rn(dy, dy)),
                             __fmul_rn(dz, dz));
        if (d2 <= R2F && j != self) {
          if (cc < KNB) { jj[cc] = (short)j; dd[cc] = d2; ++cc; }
          else {
            int mk = 0; float mv = dd[0]; int mj = jj[0];
            for (int k2 = 1; k2 < KNB; ++k2) {
              float v = dd[k2]; int vj = jj[k2];
              if (v > mv || (v == mv && vj > mj)) { mv = v; mk = k2; mj = vj; }
            }
            if (d2 < mv) { jj[mk] = (short)j; dd[mk] = d2; }
          }
        }
      }
      c = cc;
    }
    lcnt[tid] = (c > KNB) ? KNB : c;
  }
  __syncthreads();
  if (tid == 0) {
    int a = 0;
    for (int u = 0; u < 16; ++u) { starts[u] = a; a += lcnt[u]; }
    starts[16] = a;
  }
  __syncthreads();
  const int NE  = starts[16];
  const int NEp = (NE + 31) & ~31;
  {
    int u = tid >> 4, su = starts[u], cu = lcnt[u];
    for (int k = tid & 15; k < cu; k += 16) {
      epts[su + k] = (short)u;
      ejs [su + k] = nbr16[u * KNB + k];
    }
    for (int e = NE + tid; e < NEp; e += 256) { epts[e] = 16; ejs[e] = 0; }
  }
  __syncthreads();

  // ---- edge MLP subtile loop ----
  for (int es = 0; es < NEp; es += 32) {
    // stage feats (transposed): 8 threads per edge
    {
      int e = tid >> 3, q = tid & 7;
      int ge = es + e;
      int j = ejs[ge];
      const float* xr = x + ((size_t)(gp + j) << 6);
#pragma unroll
      for (int m = 0; m < 2; ++m) {
        int cc = (q << 3) + (m << 2);
        vf4 v = *(const vf4*)(xr + cc);
        fT[cc][e] = v[0]; fT[cc + 1][e] = v[1]; fT[cc + 2][e] = v[2]; fT[cc + 3][e] = v[3];
      }
      if (q == 0) {
        int p = epts[ge]; if (p > 15) p = 15;       // padded edges -> garbage, ignored
        const float* pj = pg0 + (size_t)j * 3;
        fT[64][e] = __fsub_rn(pj[0], sppos[p][0]);
        fT[65][e] = __fsub_rn(pj[1], sppos[p][1]);
        fT[66][e] = __fsub_rn(pj[2], sppos[p][2]);
      }
    }
    __syncthreads();
    // GEMM1: [32,67] x [67,128]
    {
      int c0 = (tid & 31) << 2;
      int e0 = (tid >> 5) << 2;
      float acc[4][4];
#pragma unroll
      for (int a = 0; a < 4; ++a)
#pragma unroll
        for (int b = 0; b < 4; ++b) acc[a][b] = 0.f;
      for (int k = 0; k < 67; ++k) {
        vf4 w = *(const vf4*)(W1 + (size_t)k * NH1 + c0);
        vf4 f = *(const vf4*)&fT[k][e0];
#pragma unroll
        for (int a = 0; a < 4; ++a)
#pragma unroll
          for (int b = 0; b < 4; ++b) acc[a][b] += w[a] * f[b];
      }
#pragma unroll
      for (int a = 0; a < 4; ++a) {
        float bias = b1[c0 + a];
        vf4 s;
#pragma unroll
        for (int b = 0; b < 4; ++b) s[b] = fmaxf(acc[a][b] + bias, 0.f);
        *(vf4*)&h1T[c0 + a][e0] = s;
      }
    }
    __syncthreads();
    // GEMM2: [32,128] x [128,256]
    {
      int c0 = (tid & 63) << 2;
      int e0 = (tid >> 6) << 3;
      float acc[4][8];
#pragma unroll
      for (int a = 0; a < 4; ++a)
#pragma unroll
        for (int b = 0; b < 8; ++b) acc[a][b] = 0.f;
      for (int k = 0; k < NH1; ++k) {
        vf4 w  = *(const vf4*)(W2 + (size_t)k * NH2 + c0);
        vf4 h0 = *(const vf4*)&h1T[k][e0];
        vf4 h1 = *(const vf4*)&h1T[k][e0 + 4];
#pragma unroll
        for (int a = 0; a < 4; ++a) {
#pragma unroll
          for (int b = 0; b < 4; ++b) {
            acc[a][b]     += w[a] * h0[b];
            acc[a][b + 4] += w[a] * h1[b];
          }
        }
      }
      float bias[4] = { b2[c0], b2[c0 + 1], b2[c0 + 2], b2[c0 + 3] };
      int rp = -1; float rm[4] = {0, 0, 0, 0};
#pragma unroll
      for (int ee = 0; ee < 8; ++ee) {
        int p = epts[es + e0 + ee];
        float v[4];
#pragma unroll
        for (int a = 0; a < 4; ++a) v[a] = fmaxf(acc[a][ee] + bias[a], 0.f);
        if (p != rp) {
          if (rp >= 0 && rp < 16) {
#pragma unroll
            for (int a = 0; a < 4; ++a)
              atomicMax(&aggU[rp][c0 + a], __float_as_uint(rm[a]));
          }
          rp = p;
#pragma unroll
          for (int a = 0; a < 4; ++a) rm[a] = v[a];
        } else {
#pragma unroll
          for (int a = 0; a < 4; ++a) rm[a] = fmaxf(rm[a], v[a]);
        }
      }
      if (rp >= 0 && rp < 16) {
#pragma unroll
        for (int a = 0; a < 4; ++a)
          atomicMax(&aggU[rp][c0 + a], __float_as_uint(rm[a]));
      }
    }
    __syncthreads();
  }
  // write agg (zeros stay zero for isolated points == PyG semantics)
  for (int i = tid; i < 16 * NH2; i += 256) {
    int p = i >> 8, cc = i & 255;
    agg[(size_t)(p0 + p) * NH2 + cc] = __uint_as_float(aggU[p][cc]);
  }
}

// =====================================================================
// k_out: blocks 0..1023  -> x_all = agg @ Wg + bg  (16384x256 @ 256x256)
//        blocks 1024..1279 -> x_dst (recomputed, bit-identical) + pos/batch
// =====================================================================
__global__ __launch_bounds__(256) void k_out(const float* __restrict__ agg,
                                             const float* __restrict__ Wg,
                                             const float* __restrict__ bg,
                                             const int* __restrict__ fps,
                                             const float* __restrict__ pos,
                                             float* __restrict__ out) {
  __shared__ float At[16][68];   // [k][row], padded
  __shared__ float Bt[16][64];   // [k][col]
  __shared__ int rowsL[64];
  const int bid = blockIdx.x, tid = threadIdx.x;
  const bool gath = bid >= 1024;
  const int lb  = gath ? (bid - 1024) : bid;
  const int r0  = (lb >> 2) << 6;      // row tile (x_all rows or sample ids)
  const int c0b = (lb & 3) << 6;
  if (gath && tid < 64) {
    int s = r0 + tid, gg = s >> 9;
    rowsL[tid] = (gg << 11) + fps[s];
  }
  __syncthreads();
  const int tr = tid >> 4, tc = tid & 15;
  float acc[4][4];
#pragma unroll
  for (int i = 0; i < 4; ++i)
#pragma unroll
    for (int j = 0; j < 4; ++j) acc[i][j] = 0.f;

  for (int k0 = 0; k0 < NH2; k0 += 16) {
    {
      int rr = tid >> 2, k4 = (tid & 3) << 2;
      int arow = gath ? rowsL[rr] : (r0 + rr);
      vf4 v = *(const vf4*)(agg + (size_t)arow * NH2 + k0 + k4);
      At[k4][rr] = v[0]; At[k4 + 1][rr] = v[1]; At[k4 + 2][rr] = v[2]; At[k4 + 3][rr] = v[3];
      int kk = tid >> 4, c4 = (tid & 15) << 2;
      *(vf4*)&Bt[kk][c4] = *(const vf4*)(Wg + (size_t)(k0 + kk) * NH2 + c0b + c4);
    }
    __syncthreads();
#pragma unroll
    for (int kk = 0; kk < 16; ++kk) {
      vf4 a = *(const vf4*)&At[kk][tr << 2];
      vf4 b = *(const vf4*)&Bt[kk][tc << 2];
#pragma unroll
      for (int i = 0; i < 4; ++i)
#pragma unroll
        for (int j = 0; j < 4; ++j) acc[i][j] += a[i] * b[j];
    }
    __syncthreads();
  }
  float* obase = gath ? (out + XD_OFF) : out;
#pragma unroll
  for (int i = 0; i < 4; ++i) {
    vf4 o;
#pragma unroll
    for (int j = 0; j < 4; ++j) o[j] = acc[i][j] + bg[c0b + (tc << 2) + j];
    *(vf4*)(obase + (size_t)(r0 + (tr << 2) + i) * NH2 + c0b + (tc << 2)) = o;
  }
  if (gath && c0b == 0 && tid < 64) {
    int s = r0 + tid;
    int row = rowsL[tid];
    const float* pr = pos + (size_t)row * 3;
    out[PD_OFF + s * 3]     = pr[0];
    out[PD_OFF + s * 3 + 1] = pr[1];
    out[PD_OFF + s * 3 + 2] = pr[2];
    out[BT_OFF + s] = (float)(s >> 9);
  }
}

// =====================================================================
extern "C" void kernel_launch(void* const* d_in, const int* in_sizes, int n_in,
                              void* d_out, int out_size, void* d_ws, size_t ws_size,
                              hipStream_t stream) {
  const float* x   = (const float*)d_in[0];
  const float* pos = (const float*)d_in[1];
  // d_in[2] = batch (int32) — derivable, unused
  const float* W1 = (const float*)d_in[3];
  const float* b1 = (const float*)d_in[4];
  const float* W2 = (const float*)d_in[5];
  const float* b2 = (const float*)d_in[6];
  const float* Wg = (const float*)d_in[7];
  const float* bg = (const float*)d_in[8];
  float* out = (float*)d_out;

  char* ws = (char*)d_ws;
  int*   fps = (int*)(ws);              // 4096 ints
  float* agg = (float*)(ws + 16384);    // 16384*256 floats (16 MB)

  hipLaunchKernelGGL(k_conv, dim3(BD + 1024), dim3(256), 0, stream,
                     x, pos, W1, b1, W2, b2, fps, agg);
  hipLaunchKernelGGL(k_out,  dim3(1024 + 256), dim3(256), 0, stream,
                     agg, Wg, bg, fps, pos, out);
}